// Round 1
// baseline (398.870 us; speedup 1.0000x reference)
//
#include <hip/hip_runtime.h>

typedef __attribute__((ext_vector_type(8))) short s16x8;
typedef __attribute__((ext_vector_type(4))) float f32x4;

__device__ __forceinline__ unsigned short f2b(float x) {
  unsigned int u = __float_as_uint(x);
  u = (u + 0x7fffu + ((u >> 16) & 1u)) >> 16;
  return (unsigned short)u;
}

// ---------------------------------------------------------------- cast fp32 -> bf16
__global__ void cast_kernel(const float* __restrict__ in, unsigned short* __restrict__ out, int n4) {
  int i = blockIdx.x * blockDim.x + threadIdx.x;
  if (i < n4) {
    const float4 v = ((const float4*)in)[i];
    ushort4 o;
    o.x = f2b(v.x); o.y = f2b(v.y); o.z = f2b(v.z); o.w = f2b(v.w);
    ((ushort4*)out)[i] = o;
  }
}

#define BM 128
#define BN 128
#define BK 64
#define LDA 72   // padded LDS row stride (144 B = 16*9: keeps 16B align, kills 16-way conflicts)
#define KDIM 1024

// ---------------------------------------------------------------- QKV GEMM + fused RoPE
// A [4096][1024] bf16 (x), Bt [3072][1024] bf16 (Wq|Wk|Wv rows), epilogue writes:
//   Q,K -> (B,H,S,64) bf16 (rope'd), V -> (B,H,64,S) bf16 (transposed)
__global__ __launch_bounds__(256) void gemm_qkv(
    const unsigned short* __restrict__ A,
    const unsigned short* __restrict__ Bt,
    const int* __restrict__ tok,
    unsigned short* __restrict__ Qo,
    unsigned short* __restrict__ Ko,
    unsigned short* __restrict__ Vt) {
  __shared__ unsigned short As[BM * LDA];
  __shared__ unsigned short Bs[BN * LDA];
  const int tid = threadIdx.x;
  const int m0 = blockIdx.x * BM;
  const int n0 = blockIdx.y * BN;
  const int w = tid >> 6, lane = tid & 63;
  const int ln = lane & 15, quad = lane >> 4;
  const int wm = (w >> 1) * 64, wn = (w & 1) * 64;

  const f32x4 zero = {0.f, 0.f, 0.f, 0.f};
  f32x4 acc[4][4];
#pragma unroll
  for (int i = 0; i < 4; ++i)
#pragma unroll
    for (int j = 0; j < 4; ++j) acc[i][j] = zero;

  for (int kb = 0; kb < KDIM / BK; ++kb) {
#pragma unroll
    for (int it = 0; it < 4; ++it) {
      int c = tid + it * 256;          // 1024 chunks of 8 bf16
      int row = c >> 3;
      int col = (c & 7) << 3;
      *(uint4*)(&As[row * LDA + col]) = *(const uint4*)(&A[(size_t)(m0 + row) * KDIM + kb * BK + col]);
      *(uint4*)(&Bs[row * LDA + col]) = *(const uint4*)(&Bt[(size_t)(n0 + row) * KDIM + kb * BK + col]);
    }
    __syncthreads();
#pragma unroll
    for (int ks = 0; ks < 2; ++ks) {
      s16x8 af[4], bfr[4];
#pragma unroll
      for (int i = 0; i < 4; ++i)
        af[i] = *(const s16x8*)(&As[(wm + i * 16 + ln) * LDA + ks * 32 + quad * 8]);
#pragma unroll
      for (int j = 0; j < 4; ++j)
        bfr[j] = *(const s16x8*)(&Bs[(wn + j * 16 + ln) * LDA + ks * 32 + quad * 8]);
#pragma unroll
      for (int i = 0; i < 4; ++i)
#pragma unroll
        for (int j = 0; j < 4; ++j)
          acc[i][j] = __builtin_amdgcn_mfma_f32_16x16x32_bf16(af[i], bfr[j], acc[i][j], 0, 0, 0);
    }
    __syncthreads();
  }

  // epilogue: rope for n<2048 (q,k), transpose-store for v
#pragma unroll
  for (int j = 0; j < 4; ++j) {
    int gn = n0 + wn + j * 16 + ln;
    bool isV = (gn >= 2048);                 // uniform per tile (2048 % 16 == 0)
    int e = isV ? (gn - 2048) : (gn & 1023);
    int h = e >> 6, d = e & 63;
    float inv = __expf(-0.2878231366f * (float)(d >> 1));  // 10000^(-2j/64)
#pragma unroll
    for (int i = 0; i < 4; ++i) {
      int gmb = m0 + wm + i * 16 + quad * 4;
#pragma unroll
      for (int r = 0; r < 4; ++r) {
        float val = acc[i][j][r];
        float part = __shfl_xor(val, 1, 64);  // partner column (rope pair), all lanes execute
        int m = gmb + r;
        int b = m >> 11, s = m & 2047;
        if (!isV) {
          float pos = (float)tok[s];
          float ang = pos * inv;
          float sn, cs;
          __sincosf(ang, &sn, &cs);
          float x0 = (d & 1) ? part : val;
          float x1 = (d & 1) ? val : part;
          float y = (d & 1) ? (x0 * sn + x1 * cs) : (x0 * cs - x1 * sn);
          unsigned short* dst = (gn < 1024) ? Qo : Ko;
          dst[(((size_t)b * 16 + h) * 2048 + s) * 64 + d] = f2b(y);
        } else {
          Vt[(((size_t)b * 16 + h) * 64 + d) * 2048 + s] = f2b(val);
        }
      }
    }
  }
}

// ---------------------------------------------------------------- flash attention
// grid (32 qtiles, 32 bh), block 256 = 4 waves x 16 q-rows. Uniform loop count per block.
__global__ __launch_bounds__(256) void attn_kernel(
    const unsigned short* __restrict__ Q,
    const unsigned short* __restrict__ K,
    const unsigned short* __restrict__ Vt,
    unsigned short* __restrict__ Ao) {
  __shared__ unsigned short Ps[4 * 16 * 40];  // per-wave 16x32 P, stride 40 (80 B, aligned+conflict-lite)
  const int tid = threadIdx.x;
  const int w = tid >> 6, lane = tid & 63;
  const int ln = lane & 15, quad = lane >> 4;
  const int bh = blockIdx.y;
  const int b = bh >> 4, h = bh & 15;
  const int qb = blockIdx.x * 64 + w * 16;

  const unsigned short* Qb = Q + (size_t)bh * 2048 * 64;
  const unsigned short* Kb = K + (size_t)bh * 2048 * 64;
  const unsigned short* Vb = Vt + (size_t)bh * 64 * 2048;

  s16x8 aq[2];
#pragma unroll
  for (int ks = 0; ks < 2; ++ks)
    aq[ks] = *(const s16x8*)(&Qb[(size_t)(qb + ln) * 64 + ks * 32 + quad * 8]);

  const f32x4 zero = {0.f, 0.f, 0.f, 0.f};
  f32x4 o[4];
#pragma unroll
  for (int j = 0; j < 4; ++j) o[j] = zero;
  float m_i[4] = {-1e30f, -1e30f, -1e30f, -1e30f};
  float l_i[4] = {0.f, 0.f, 0.f, 0.f};

  const int kend = blockIdx.x * 64 + 63;  // uniform across the block
  for (int k0 = 0; k0 <= kend; k0 += 32) {
    f32x4 st[2];
#pragma unroll
    for (int t = 0; t < 2; ++t) {
      s16x8 bk0 = *(const s16x8*)(&Kb[(size_t)(k0 + t * 16 + ln) * 64 + quad * 8]);
      s16x8 bk1 = *(const s16x8*)(&Kb[(size_t)(k0 + t * 16 + ln) * 64 + 32 + quad * 8]);
      f32x4 s = zero;
      s = __builtin_amdgcn_mfma_f32_16x16x32_bf16(aq[0], bk0, s, 0, 0, 0);
      s = __builtin_amdgcn_mfma_f32_16x16x32_bf16(aq[1], bk1, s, 0, 0, 0);
      st[t] = s;
    }
    float alpha[4];
#pragma unroll
    for (int r = 0; r < 4; ++r) {
      int row = qb + quad * 4 + r;
      float a0 = st[0][r] * 0.125f;
      float a1 = st[1][r] * 0.125f;
      if (k0 + ln > row) a0 = -1e30f;        // causal mask (positions are arange)
      if (k0 + 16 + ln > row) a1 = -1e30f;
      float mr = fmaxf(a0, a1);
#pragma unroll
      for (int dd = 1; dd < 16; dd <<= 1) mr = fmaxf(mr, __shfl_xor(mr, dd, 64));
      float mn = fmaxf(m_i[r], mr);
      float al = __expf(m_i[r] - mn);
      float p0 = __expf(a0 - mn);
      float p1 = __expf(a1 - mn);
      float rs = p0 + p1;
#pragma unroll
      for (int dd = 1; dd < 16; dd <<= 1) rs += __shfl_xor(rs, dd, 64);
      m_i[r] = mn;
      l_i[r] = l_i[r] * al + rs;
      alpha[r] = al;
      Ps[(w * 16 + quad * 4 + r) * 40 + ln] = f2b(p0);
      Ps[(w * 16 + quad * 4 + r) * 40 + 16 + ln] = f2b(p1);
    }
#pragma unroll
    for (int j = 0; j < 4; ++j) {
      o[j][0] *= alpha[0]; o[j][1] *= alpha[1];
      o[j][2] *= alpha[2]; o[j][3] *= alpha[3];
    }
    __syncthreads();  // intra-wave LDS write->read ordering (uniform loop => legal)
    s16x8 pa = *(const s16x8*)(&Ps[(w * 16 + ln) * 40 + quad * 8]);
#pragma unroll
    for (int j = 0; j < 4; ++j) {
      s16x8 vb = *(const s16x8*)(&Vb[(size_t)(j * 16 + ln) * 2048 + k0 + quad * 8]);
      o[j] = __builtin_amdgcn_mfma_f32_16x16x32_bf16(pa, vb, o[j], 0, 0, 0);
    }
    __syncthreads();  // P-read of iter i before P-write of iter i+1
  }
#pragma unroll
  for (int r = 0; r < 4; ++r) {
    float invl = 1.0f / l_i[r];
    int srow = qb + quad * 4 + r;
    size_t base = ((size_t)b * 2048 + srow) * 1024 + h * 64;
#pragma unroll
    for (int j = 0; j < 4; ++j)
      Ao[base + j * 16 + ln] = f2b(o[j][r] * invl);
  }
}

// ---------------------------------------------------------------- output projection GEMM
__global__ __launch_bounds__(256) void gemm_out(
    const unsigned short* __restrict__ A,   // attn (4096 x 1024) bf16
    const unsigned short* __restrict__ Bt,  // Wo (1024 x 1024) bf16
    float* __restrict__ out) {
  __shared__ unsigned short As[BM * LDA];
  __shared__ unsigned short Bs[BN * LDA];
  const int tid = threadIdx.x;
  const int m0 = blockIdx.x * BM;
  const int n0 = blockIdx.y * BN;
  const int w = tid >> 6, lane = tid & 63;
  const int ln = lane & 15, quad = lane >> 4;
  const int wm = (w >> 1) * 64, wn = (w & 1) * 64;

  const f32x4 zero = {0.f, 0.f, 0.f, 0.f};
  f32x4 acc[4][4];
#pragma unroll
  for (int i = 0; i < 4; ++i)
#pragma unroll
    for (int j = 0; j < 4; ++j) acc[i][j] = zero;

  for (int kb = 0; kb < KDIM / BK; ++kb) {
#pragma unroll
    for (int it = 0; it < 4; ++it) {
      int c = tid + it * 256;
      int row = c >> 3;
      int col = (c & 7) << 3;
      *(uint4*)(&As[row * LDA + col]) = *(const uint4*)(&A[(size_t)(m0 + row) * KDIM + kb * BK + col]);
      *(uint4*)(&Bs[row * LDA + col]) = *(const uint4*)(&Bt[(size_t)(n0 + row) * KDIM + kb * BK + col]);
    }
    __syncthreads();
#pragma unroll
    for (int ks = 0; ks < 2; ++ks) {
      s16x8 af[4], bfr[4];
#pragma unroll
      for (int i = 0; i < 4; ++i)
        af[i] = *(const s16x8*)(&As[(wm + i * 16 + ln) * LDA + ks * 32 + quad * 8]);
#pragma unroll
      for (int j = 0; j < 4; ++j)
        bfr[j] = *(const s16x8*)(&Bs[(wn + j * 16 + ln) * LDA + ks * 32 + quad * 8]);
#pragma unroll
      for (int i = 0; i < 4; ++i)
#pragma unroll
        for (int j = 0; j < 4; ++j)
          acc[i][j] = __builtin_amdgcn_mfma_f32_16x16x32_bf16(af[i], bfr[j], acc[i][j], 0, 0, 0);
    }
    __syncthreads();
  }
#pragma unroll
  for (int i = 0; i < 4; ++i) {
    int gmb = m0 + wm + i * 16 + quad * 4;
#pragma unroll
    for (int j = 0; j < 4; ++j) {
      int gn = n0 + wn + j * 16 + ln;
#pragma unroll
      for (int r = 0; r < 4; ++r)
        out[(size_t)(gmb + r) * 1024 + gn] = acc[i][j][r];
    }
  }
}

// ---------------------------------------------------------------- launch
extern "C" void kernel_launch(void* const* d_in, const int* in_sizes, int n_in,
                              void* d_out, int out_size, void* d_ws, size_t ws_size,
                              hipStream_t stream) {
  const float* x  = (const float*)d_in[0];
  const float* Wq = (const float*)d_in[1];
  const float* Wk = (const float*)d_in[2];
  const float* Wv = (const float*)d_in[3];
  const float* Wo = (const float*)d_in[4];
  const int* tok  = (const int*)d_in[5];
  float* out = (float*)d_out;

  char* ws = (char*)d_ws;
  unsigned short* xb   = (unsigned short*)(ws);                        // 8 MB: x bf16 [4096][1024]
  unsigned short* Wcat = (unsigned short*)(ws + (8ull  << 20));        // 6 MB: Wq|Wk|Wv bf16 [3072][1024]
  unsigned short* Wob  = (unsigned short*)(ws + (14ull << 20));        // 2 MB: Wo bf16
  unsigned short* Qb   = (unsigned short*)(ws + (16ull << 20));        // 8 MB: (B,H,S,64)
  unsigned short* Kb   = (unsigned short*)(ws + (24ull << 20));        // 8 MB
  unsigned short* Vtb  = (unsigned short*)(ws + (32ull << 20));        // 8 MB: (B,H,64,S)
  unsigned short* Ab   = (unsigned short*)(ws + (40ull << 20));        // 8 MB: attn (4096 x 1024)

  cast_kernel<<<dim3(4096), dim3(256), 0, stream>>>(x,  xb,   1048576);
  cast_kernel<<<dim3(1024), dim3(256), 0, stream>>>(Wq, Wcat,            262144);
  cast_kernel<<<dim3(1024), dim3(256), 0, stream>>>(Wk, Wcat + (1u<<20), 262144);
  cast_kernel<<<dim3(1024), dim3(256), 0, stream>>>(Wv, Wcat + (2u<<20), 262144);
  cast_kernel<<<dim3(1024), dim3(256), 0, stream>>>(Wo, Wob,             262144);

  gemm_qkv<<<dim3(32, 24), dim3(256), 0, stream>>>(xb, Wcat, tok, Qb, Kb, Vtb);
  attn_kernel<<<dim3(32, 32), dim3(256), 0, stream>>>(Qb, Kb, Vtb, Ab);
  gemm_out<<<dim3(32, 8), dim3(256), 0, stream>>>(Ab, Wob, out);
}

// Round 2
// 289.470 us; speedup vs baseline: 1.3779x; 1.3779x over previous
//
#include <hip/hip_runtime.h>
#include <hip/hip_bf16.h>

typedef __attribute__((ext_vector_type(8))) short s16x8;
typedef __attribute__((ext_vector_type(4))) float f32x4;

__device__ __forceinline__ unsigned short f2b(float x) {
  unsigned int u = __float_as_uint(x);
  u = (u + 0x7fffu + ((u >> 16) & 1u)) >> 16;
  return (unsigned short)u;
}

__device__ __forceinline__ unsigned int pkbf(float a, float b) {
  // low16 = bf16(a), high16 = bf16(b)
  return (unsigned int)f2b(a) | ((unsigned int)f2b(b) << 16);
}

// ---------------------------------------------------------------- cast fp32 -> bf16
__global__ void cast_kernel(const float* __restrict__ in, unsigned short* __restrict__ out, int n4) {
  int i = blockIdx.x * blockDim.x + threadIdx.x;
  if (i < n4) {
    const float4 v = ((const float4*)in)[i];
    ushort4 o;
    o.x = f2b(v.x); o.y = f2b(v.y); o.z = f2b(v.z); o.w = f2b(v.w);
    ((ushort4*)out)[i] = o;
  }
}

#define BM 128
#define BN 128
#define BK 64
#define LDA 72   // padded LDS row stride
#define KDIM 1024

// ---------------------------------------------------------------- QKV GEMM + fused RoPE
__global__ __launch_bounds__(256) void gemm_qkv(
    const unsigned short* __restrict__ A,
    const unsigned short* __restrict__ Bt,
    const int* __restrict__ tok,
    unsigned short* __restrict__ Qo,
    unsigned short* __restrict__ Ko,
    unsigned short* __restrict__ Vt) {
  __shared__ unsigned short As[BM * LDA];
  __shared__ unsigned short Bs[BN * LDA];
  const int tid = threadIdx.x;
  const int m0 = blockIdx.x * BM;
  const int n0 = blockIdx.y * BN;
  const int w = tid >> 6, lane = tid & 63;
  const int ln = lane & 15, quad = lane >> 4;
  const int wm = (w >> 1) * 64, wn = (w & 1) * 64;

  const f32x4 zero = {0.f, 0.f, 0.f, 0.f};
  f32x4 acc[4][4];
#pragma unroll
  for (int i = 0; i < 4; ++i)
#pragma unroll
    for (int j = 0; j < 4; ++j) acc[i][j] = zero;

  for (int kb = 0; kb < KDIM / BK; ++kb) {
#pragma unroll
    for (int it = 0; it < 4; ++it) {
      int c = tid + it * 256;
      int row = c >> 3;
      int col = (c & 7) << 3;
      *(uint4*)(&As[row * LDA + col]) = *(const uint4*)(&A[(size_t)(m0 + row) * KDIM + kb * BK + col]);
      *(uint4*)(&Bs[row * LDA + col]) = *(const uint4*)(&Bt[(size_t)(n0 + row) * KDIM + kb * BK + col]);
    }
    __syncthreads();
#pragma unroll
    for (int ks = 0; ks < 2; ++ks) {
      s16x8 af[4], bfr[4];
#pragma unroll
      for (int i = 0; i < 4; ++i)
        af[i] = *(const s16x8*)(&As[(wm + i * 16 + ln) * LDA + ks * 32 + quad * 8]);
#pragma unroll
      for (int j = 0; j < 4; ++j)
        bfr[j] = *(const s16x8*)(&Bs[(wn + j * 16 + ln) * LDA + ks * 32 + quad * 8]);
#pragma unroll
      for (int i = 0; i < 4; ++i)
#pragma unroll
        for (int j = 0; j < 4; ++j)
          acc[i][j] = __builtin_amdgcn_mfma_f32_16x16x32_bf16(af[i], bfr[j], acc[i][j], 0, 0, 0);
    }
    __syncthreads();
  }

#pragma unroll
  for (int j = 0; j < 4; ++j) {
    int gn = n0 + wn + j * 16 + ln;
    bool isV = (gn >= 2048);
    int e = isV ? (gn - 2048) : (gn & 1023);
    int h = e >> 6, d = e & 63;
    float inv = __expf(-0.2878231366f * (float)(d >> 1));
#pragma unroll
    for (int i = 0; i < 4; ++i) {
      int gmb = m0 + wm + i * 16 + quad * 4;
#pragma unroll
      for (int r = 0; r < 4; ++r) {
        float val = acc[i][j][r];
        float part = __shfl_xor(val, 1, 64);
        int m = gmb + r;
        int b = m >> 11, s = m & 2047;
        if (!isV) {
          float pos = (float)tok[s];
          float ang = pos * inv;
          float sn, cs;
          __sincosf(ang, &sn, &cs);
          float x0 = (d & 1) ? part : val;
          float x1 = (d & 1) ? val : part;
          float y = (d & 1) ? (x0 * sn + x1 * cs) : (x0 * cs - x1 * sn);
          unsigned short* dst = (gn < 1024) ? Qo : Ko;
          dst[(((size_t)b * 16 + h) * 2048 + s) * 64 + d] = f2b(y);
        } else {
          Vt[(((size_t)b * 16 + h) * 64 + d) * 2048 + s] = f2b(val);
        }
      }
    }
  }
}

// ---------------------------------------------------------------- flash attention (transposed, barrier-free)
// Computes S^T = K·Q^T so softmax reduces over quads (2 shuffles), P^T moves to
// PV B-operand layout fully in-register, O accumulated as O^T = V^T·P^T.
// Block = 128 threads = 2 waves; each wave owns 32 q-rows. No LDS, no barriers.
__global__ __launch_bounds__(128) void attn_kernel(
    const unsigned short* __restrict__ Q,
    const unsigned short* __restrict__ K,
    const unsigned short* __restrict__ Vt,
    unsigned short* __restrict__ Ao) {
  const int tid = threadIdx.x;
  const int w = tid >> 6, lane = tid & 63;
  const int ln = lane & 15, quad = lane >> 4;
  const int bh = blockIdx.y;
  const int b = bh >> 4, h = bh & 15;
  // heavy q-tiles first (assuming roughly ascending dispatch) for causal balance
  const int qb = (gridDim.x - 1 - blockIdx.x) * 64 + w * 32;

  const unsigned short* Qb = Q + (size_t)bh * 2048 * 64;
  const unsigned short* Kb = K + (size_t)bh * 2048 * 64;
  const unsigned short* Vb = Vt + (size_t)bh * 64 * 2048;

  // Q as B-operand frags: B[k=d][n=q], n=ln, k=quad*8+j (+32h)
  s16x8 bq[2][2];
#pragma unroll
  for (int u = 0; u < 2; ++u)
#pragma unroll
    for (int hh = 0; hh < 2; ++hh)
      bq[u][hh] = *(const s16x8*)(&Qb[(size_t)(qb + u * 16 + ln) * 64 + hh * 32 + quad * 8]);

  const f32x4 zero = {0.f, 0.f, 0.f, 0.f};
  f32x4 o[2][4];
#pragma unroll
  for (int u = 0; u < 2; ++u)
#pragma unroll
    for (int j = 0; j < 4; ++j) o[u][j] = zero;
  float m_i[2] = {-3e38f, -3e38f};
  float l_i[2] = {0.f, 0.f};

  for (int k0 = 0; k0 <= qb + 31; k0 += 64) {
    // K rows as A-operand frags (shared by both q-subtiles)
    s16x8 ka[4][2];
#pragma unroll
    for (int t = 0; t < 4; ++t)
#pragma unroll
      for (int hh = 0; hh < 2; ++hh)
        ka[t][hh] = *(const s16x8*)(&Kb[(size_t)(k0 + t * 16 + ln) * 64 + hh * 32 + quad * 8]);
    // V^T as A-operand frags: A[m=d][k], d=j*16+ln, k=k0+hh*32+quad*8+e
    s16x8 va[4][2];
#pragma unroll
    for (int j = 0; j < 4; ++j)
#pragma unroll
      for (int hh = 0; hh < 2; ++hh)
        va[j][hh] = *(const s16x8*)(&Vb[(size_t)(j * 16 + ln) * 2048 + k0 + hh * 32 + quad * 8]);

#pragma unroll
    for (int u = 0; u < 2; ++u) {
      const int q = qb + u * 16 + ln;  // this lane's query column
      // S^T tiles: st[t][r] = S^T[k0+t*16+quad*4+r][q]
      f32x4 st[4];
#pragma unroll
      for (int t = 0; t < 4; ++t) {
        f32x4 s = __builtin_amdgcn_mfma_f32_16x16x32_bf16(ka[t][0], bq[u][0], zero, 0, 0, 0);
        st[t] = __builtin_amdgcn_mfma_f32_16x16x32_bf16(ka[t][1], bq[u][1], s, 0, 0, 0);
      }
      // scale + causal mask + local max
      float lm = -3e38f;
#pragma unroll
      for (int t = 0; t < 4; ++t)
#pragma unroll
        for (int r = 0; r < 4; ++r) {
          int kk = k0 + t * 16 + quad * 4 + r;
          float v = st[t][r] * 0.125f;
          v = (kk > q) ? -3e38f : v;
          st[t][r] = v;
          lm = fmaxf(lm, v);
        }
      lm = fmaxf(lm, __shfl_xor(lm, 16, 64));
      lm = fmaxf(lm, __shfl_xor(lm, 32, 64));
      float mn = fmaxf(m_i[u], lm);
      float al = __expf(m_i[u] - mn);
      float rs = 0.f;
#pragma unroll
      for (int t = 0; t < 4; ++t)
#pragma unroll
        for (int r = 0; r < 4; ++r) {
          float p = __expf(st[t][r] - mn);
          st[t][r] = p;
          rs += p;
        }
      rs += __shfl_xor(rs, 16, 64);
      rs += __shfl_xor(rs, 32, 64);
      m_i[u] = mn;
      l_i[u] = l_i[u] * al + rs;
#pragma unroll
      for (int j = 0; j < 4; ++j) o[u][j] *= al;
      // pack P^T rows to bf16 pairs: pk[t][pi] = rows (quad*4+2pi, +1) of tile t, col ln
      unsigned int pk[4][2];
#pragma unroll
      for (int t = 0; t < 4; ++t) {
        pk[t][0] = pkbf(st[t][0], st[t][1]);
        pk[t][1] = pkbf(st[t][2], st[t][3]);
      }
      // assemble PV B-operand frags in-register and accumulate O^T
#pragma unroll
      for (int hh = 0; hh < 2; ++hh) {
        int bi[4];
#pragma unroll
        for (int v = 0; v < 4; ++v) {
          int src = ln + 16 * ((quad & 1) * 2 + (v >> 1));
          int lo = __shfl((int)pk[2 * hh][v & 1], src, 64);
          int hi = __shfl((int)pk[2 * hh + 1][v & 1], src, 64);
          bi[v] = (quad < 2) ? lo : hi;
        }
        s16x8 pb = *(s16x8*)bi;
#pragma unroll
        for (int j = 0; j < 4; ++j)
          o[u][j] = __builtin_amdgcn_mfma_f32_16x16x32_bf16(va[j][hh], pb, o[u][j], 0, 0, 0);
      }
    }
  }
  // epilogue: O^T layout -> Ao[(b,s,h*64+d)], lane holds one q-row (s), 16 d values
#pragma unroll
  for (int u = 0; u < 2; ++u) {
    float invl = 1.0f / l_i[u];
    int s = qb + u * 16 + ln;
    size_t base = ((size_t)b * 2048 + s) * 1024 + h * 64;
#pragma unroll
    for (int j = 0; j < 4; ++j) {
      ushort4 o4;
      o4.x = f2b(o[u][j][0] * invl);
      o4.y = f2b(o[u][j][1] * invl);
      o4.z = f2b(o[u][j][2] * invl);
      o4.w = f2b(o[u][j][3] * invl);
      *(ushort4*)(&Ao[base + j * 16 + quad * 4]) = o4;
    }
  }
}

// ---------------------------------------------------------------- output projection GEMM
__global__ __launch_bounds__(256) void gemm_out(
    const unsigned short* __restrict__ A,
    const unsigned short* __restrict__ Bt,
    float* __restrict__ out) {
  __shared__ unsigned short As[BM * LDA];
  __shared__ unsigned short Bs[BN * LDA];
  const int tid = threadIdx.x;
  const int m0 = blockIdx.x * BM;
  const int n0 = blockIdx.y * BN;
  const int w = tid >> 6, lane = tid & 63;
  const int ln = lane & 15, quad = lane >> 4;
  const int wm = (w >> 1) * 64, wn = (w & 1) * 64;

  const f32x4 zero = {0.f, 0.f, 0.f, 0.f};
  f32x4 acc[4][4];
#pragma unroll
  for (int i = 0; i < 4; ++i)
#pragma unroll
    for (int j = 0; j < 4; ++j) acc[i][j] = zero;

  for (int kb = 0; kb < KDIM / BK; ++kb) {
#pragma unroll
    for (int it = 0; it < 4; ++it) {
      int c = tid + it * 256;
      int row = c >> 3;
      int col = (c & 7) << 3;
      *(uint4*)(&As[row * LDA + col]) = *(const uint4*)(&A[(size_t)(m0 + row) * KDIM + kb * BK + col]);
      *(uint4*)(&Bs[row * LDA + col]) = *(const uint4*)(&Bt[(size_t)(n0 + row) * KDIM + kb * BK + col]);
    }
    __syncthreads();
#pragma unroll
    for (int ks = 0; ks < 2; ++ks) {
      s16x8 af[4], bfr[4];
#pragma unroll
      for (int i = 0; i < 4; ++i)
        af[i] = *(const s16x8*)(&As[(wm + i * 16 + ln) * LDA + ks * 32 + quad * 8]);
#pragma unroll
      for (int j = 0; j < 4; ++j)
        bfr[j] = *(const s16x8*)(&Bs[(wn + j * 16 + ln) * LDA + ks * 32 + quad * 8]);
#pragma unroll
      for (int i = 0; i < 4; ++i)
#pragma unroll
        for (int j = 0; j < 4; ++j)
          acc[i][j] = __builtin_amdgcn_mfma_f32_16x16x32_bf16(af[i], bfr[j], acc[i][j], 0, 0, 0);
    }
    __syncthreads();
  }
#pragma unroll
  for (int i = 0; i < 4; ++i) {
    int gmb = m0 + wm + i * 16 + quad * 4;
#pragma unroll
    for (int j = 0; j < 4; ++j) {
      int gn = n0 + wn + j * 16 + ln;
#pragma unroll
      for (int r = 0; r < 4; ++r)
        out[(size_t)(gmb + r) * 1024 + gn] = acc[i][j][r];
    }
  }
}

// ---------------------------------------------------------------- launch
extern "C" void kernel_launch(void* const* d_in, const int* in_sizes, int n_in,
                              void* d_out, int out_size, void* d_ws, size_t ws_size,
                              hipStream_t stream) {
  const float* x  = (const float*)d_in[0];
  const float* Wq = (const float*)d_in[1];
  const float* Wk = (const float*)d_in[2];
  const float* Wv = (const float*)d_in[3];
  const float* Wo = (const float*)d_in[4];
  const int* tok  = (const int*)d_in[5];
  float* out = (float*)d_out;

  char* ws = (char*)d_ws;
  unsigned short* xb   = (unsigned short*)(ws);
  unsigned short* Wcat = (unsigned short*)(ws + (8ull  << 20));
  unsigned short* Wob  = (unsigned short*)(ws + (14ull << 20));
  unsigned short* Qb   = (unsigned short*)(ws + (16ull << 20));
  unsigned short* Kb   = (unsigned short*)(ws + (24ull << 20));
  unsigned short* Vtb  = (unsigned short*)(ws + (32ull << 20));
  unsigned short* Ab   = (unsigned short*)(ws + (40ull << 20));

  cast_kernel<<<dim3(4096), dim3(256), 0, stream>>>(x,  xb,   1048576);
  cast_kernel<<<dim3(1024), dim3(256), 0, stream>>>(Wq, Wcat,            262144);
  cast_kernel<<<dim3(1024), dim3(256), 0, stream>>>(Wk, Wcat + (1u<<20), 262144);
  cast_kernel<<<dim3(1024), dim3(256), 0, stream>>>(Wv, Wcat + (2u<<20), 262144);
  cast_kernel<<<dim3(1024), dim3(256), 0, stream>>>(Wo, Wob,             262144);

  gemm_qkv<<<dim3(32, 24), dim3(256), 0, stream>>>(xb, Wcat, tok, Qb, Kb, Vtb);
  attn_kernel<<<dim3(32, 32), dim3(128), 0, stream>>>(Qb, Kb, Vtb, Ab);
  gemm_out<<<dim3(32, 8), dim3(256), 0, stream>>>(Ab, Wob, out);
}